// Round 3
// baseline (236.864 us; speedup 1.0000x reference)
//
#include <hip/hip_runtime.h>
#include <hip/hip_cooperative_groups.h>
#include <math.h>

namespace cg = cooperative_groups;

#define HOP 256
#define T_START 120
#define NFREQ 19
#define KMIN 13
#define NANGLES 18001
#define NBLK 71   // ceil(18001/256); blocks 0..18 also carry the 76 DFT waves

// ---------------------------------------------------------------------------
// Single cooperative kernel.
//  Phase 0 (all 18176 threads): per-angle trig (3 libm f64 calls) — runs
//    concurrently with phase 1 on blocks 19..70.
//  Phase 1 (waves 0..75, i.e. blocks 0..18 x 4 waves): windowed DFT for one
//    (freq k, frame t). Each lane handles 8 samples (n = lane + 64j) for all
//    4 mics via one float4 load. Trig by recurrence (identical op sequence to
//    the previous k_dft). Lane 0 writes 8 doubles to ws.
//  grid.sync()  (+ explicit agent release/acquire fences for cross-XCD L2)
//  Phase 2 (lanes 0..18 of wave 0, redundantly per block): 4x4 complex
//    Jacobi, 5 sweeps, disjoint-plane pairing — identical op sequence — then
//    the 7-entry lag table per freq into LDS.
//  Phase 3 (all threads): denom(phi) = T0 + 2*Re[Q1 e^{i phi} + Q2 e^{2i phi}
//    + Q3 e^{3i phi}], reciprocal-sum over the 19 freqs.
// ---------------------------------------------------------------------------
__constant__ double C8[8] = {1.0, 0.70710678118654752, 0.0, -0.70710678118654752,
                             -1.0, -0.70710678118654752, 0.0, 0.70710678118654752};
__constant__ double S8[8] = {0.0, 0.70710678118654752, 1.0, 0.70710678118654752,
                             0.0, -0.70710678118654752, -1.0, -0.70710678118654752};

__global__ __launch_bounds__(256, 1) void k_all(const float4* __restrict__ x4,
                                                double* __restrict__ ws,
                                                float* __restrict__ out) {
    __shared__ double tb[NFREQ * 7];
    const int tid = threadIdx.x;
    const int i   = blockIdx.x * 256 + tid;

    // ---- phase 0: per-angle trig ----
    const double deg = -90.0 + 0.01 * (double)i;
    const double sth = sin(deg * (M_PI / 180.0));
    const double KC  = 2.0 * M_PI * 0.1 / 343.0;
    const double a   = KC * sth;
    double c0, s0, cd, sd;
    sincos(a * (31.25 * (double)KMIN), &s0, &c0);
    sincos(a * 31.25, &sd, &cd);

    // ---- phase 1: DFT (76 waves) ----
    const int wid = (blockIdx.x << 2) + (tid >> 6);   // global wave id
    if (wid < NFREQ * 4) {
        const int k    = wid >> 2;
        const int t    = wid & 3;
        const int lane = tid & 63;
        const int kact = KMIN + k;
        const int base = (T_START - 1 + t) * HOP;

        // window: (sw,cw) = sin/cos(pi*lane/512); step over 64 samples = pi/8
        const double cw8 = 0.92387953251128675613;  // cos(pi/8)
        const double sw8 = 0.38268343236508977173;  // sin(pi/8)
        double sw, cw;
        sincospi((double)lane / 512.0, &sw, &cw);

        // DFT phase: theta_n = pi*kact*n/256; start at n=lane, step pi*kact/4
        double sp, cp;
        sincospi((double)(kact * lane) / 256.0, &sp, &cp);
        const int m = kact & 7;
        const double cdp = C8[m], sdp = S8[m];

        double xr0 = 0, xi0 = 0, xr1 = 0, xi1 = 0;
        double xr2 = 0, xi2 = 0, xr3 = 0, xi3 = 0;
#pragma unroll
        for (int j = 0; j < 8; ++j) {
            const float4 v = x4[base + lane + 64 * j];
            const double wr = sw * cp;   // w[n]*cos(theta)
            const double wi = sw * sp;   // w[n]*sin(theta)
            xr0 += (double)v.x * wr;  xi0 -= (double)v.x * wi;
            xr1 += (double)v.y * wr;  xi1 -= (double)v.y * wi;
            xr2 += (double)v.z * wr;  xi2 -= (double)v.z * wi;
            xr3 += (double)v.w * wr;  xi3 -= (double)v.w * wi;
            // advance window angle by pi/8
            const double nw = sw * cw8 + cw * sw8;
            cw = cw * cw8 - sw * sw8;
            sw = nw;
            // advance DFT angle by pi*kact/4
            const double np = sp * cdp + cp * sdp;
            cp = cp * cdp - sp * sdp;
            sp = np;
        }
#pragma unroll
        for (int off = 32; off > 0; off >>= 1) {
            xr0 += __shfl_down(xr0, off, 64);  xi0 += __shfl_down(xi0, off, 64);
            xr1 += __shfl_down(xr1, off, 64);  xi1 += __shfl_down(xi1, off, 64);
            xr2 += __shfl_down(xr2, off, 64);  xi2 += __shfl_down(xi2, off, 64);
            xr3 += __shfl_down(xr3, off, 64);  xi3 += __shfl_down(xi3, off, 64);
        }
        if (lane == 0) {
            const int idx = k * 16 + t * 4;   // f*16 + t*4 + c
            ws[2 * (idx + 0)] = xr0;  ws[2 * (idx + 0) + 1] = xi0;
            ws[2 * (idx + 1)] = xr1;  ws[2 * (idx + 1) + 1] = xi1;
            ws[2 * (idx + 2)] = xr2;  ws[2 * (idx + 2) + 1] = xi2;
            ws[2 * (idx + 3)] = xr3;  ws[2 * (idx + 3) + 1] = xi3;
        }
        __threadfence();   // release: X coeffs visible device-wide before sync
    }

    cg::this_grid().sync();

    // ---- phase 2: per-frequency Jacobi (lanes 0..18 of wave 0, per block) --
    if (tid < NFREQ) {
        __threadfence();   // acquire: don't read stale (poisoned) L2 lines
        const int f = tid;
        double Xr[4][4], Xi[4][4];   // [t][c]
#pragma unroll
        for (int t = 0; t < 4; ++t)
#pragma unroll
            for (int c = 0; c < 4; ++c) {
                const int idx = f * 16 + t * 4 + c;
                Xr[t][c] = ws[2 * idx];
                Xi[t][c] = ws[2 * idx + 1];
            }

        double Ar[4][4], Ai[4][4], Vr[4][4], Vi[4][4];
#pragma unroll
        for (int aa = 0; aa < 4; ++aa)
#pragma unroll
            for (int dd = 0; dd < 4; ++dd) {
                double ar = 0.0, ai = 0.0;
#pragma unroll
                for (int t = 0; t < 4; ++t) {
                    ar += Xr[t][aa] * Xr[t][dd] + Xi[t][aa] * Xi[t][dd];
                    ai += Xi[t][aa] * Xr[t][dd] - Xr[t][aa] * Xi[t][dd];
                }
                Ar[aa][dd] = 0.25 * ar;
                Ai[aa][dd] = 0.25 * ai;
                Vr[aa][dd] = (aa == dd) ? 1.0 : 0.0;
                Vi[aa][dd] = 0.0;
            }

        // Disjoint-plane pairing: (0,1)(2,3) | (0,2)(1,3) | (0,3)(1,2) —
        // adjacent rotations are data-independent (sqrt/div latencies overlap).
        const int PP[6] = {0, 2, 0, 1, 0, 1};
        const int QQ[6] = {1, 3, 2, 3, 3, 2};
        for (int sweep = 0; sweep < 5; ++sweep) {
#pragma unroll
            for (int r6 = 0; r6 < 6; ++r6) {
                const int p = PP[r6], q = QQ[r6];
                const double zr = Ar[p][q], zi = Ai[p][q];
                const double rr = sqrt(zr * zr + zi * zi);
                if (rr < 1e-30) continue;
                const double tau = (Ar[q][q] - Ar[p][p]) / (2.0 * rr);
                const double sq  = sqrt(tau * tau + 1.0);
                const double tt  = (tau >= 0.0) ? (-1.0 / (tau + sq)) : (1.0 / (sq - tau));
                const double cc  = 1.0 / sqrt(1.0 + tt * tt);
                const double sg  = tt * cc;
                const double inv_r = 1.0 / rr;
                const double sr =  sg * zr * inv_r;
                const double si = -sg * zi * inv_r;
                // A <- A * U
#pragma unroll
                for (int kk = 0; kk < 4; ++kk) {
                    const double apr = Ar[kk][p], api = Ai[kk][p];
                    const double aqr = Ar[kk][q], aqi = Ai[kk][q];
                    Ar[kk][p] = cc * apr + sr * aqr - si * aqi;
                    Ai[kk][p] = cc * api + sr * aqi + si * aqr;
                    Ar[kk][q] = cc * aqr - (sr * apr + si * api);
                    Ai[kk][q] = cc * aqi - (sr * api - si * apr);
                }
                // A <- U^H * A
#pragma unroll
                for (int kk = 0; kk < 4; ++kk) {
                    const double apr = Ar[p][kk], api = Ai[p][kk];
                    const double aqr = Ar[q][kk], aqi = Ai[q][kk];
                    Ar[p][kk] = cc * apr + sr * aqr + si * aqi;
                    Ai[p][kk] = cc * api + sr * aqi - si * aqr;
                    Ar[q][kk] = cc * aqr - (sr * apr - si * api);
                    Ai[q][kk] = cc * aqi - (sr * api + si * apr);
                }
                // V <- V * U
#pragma unroll
                for (int kk = 0; kk < 4; ++kk) {
                    const double vpr = Vr[kk][p], vpi = Vi[kk][p];
                    const double vqr = Vr[kk][q], vqi = Vi[kk][q];
                    Vr[kk][p] = cc * vpr + sr * vqr - si * vqi;
                    Vi[kk][p] = cc * vpi + sr * vqi + si * vqr;
                    Vr[kk][q] = cc * vqr - (sr * vpr + si * vpi);
                    Vi[kk][q] = cc * vqi - (sr * vpi - si * vpr);
                }
            }
        }

        // two smallest eigenvalues -> noise subspace
        double dg[4] = {Ar[0][0], Ar[1][1], Ar[2][2], Ar[3][3]};
        int i0 = 0;
#pragma unroll
        for (int j = 1; j < 4; ++j)
            if (dg[j] < dg[i0]) i0 = j;
        int i1 = (i0 == 0) ? 1 : 0;
#pragma unroll
        for (int j = 0; j < 4; ++j)
            if (j != i0 && dg[j] < dg[i1]) i1 = j;

        double u0r[4], u0i[4], u1r[4], u1i[4];
#pragma unroll
        for (int c = 0; c < 4; ++c) {
            u0r[c] = Vr[c][i0]; u0i[c] = Vi[c][i0];
            u1r[c] = Vr[c][i1]; u1i[c] = Vi[c][i1];
        }

        double T0 = 0.0;
#pragma unroll
        for (int c = 0; c < 4; ++c)
            T0 += u0r[c] * u0r[c] + u0i[c] * u0i[c] + u1r[c] * u1r[c] + u1i[c] * u1i[c];
        double q1r = 0, q1i = 0, q2r = 0, q2i = 0, q3r = 0, q3i = 0;
#pragma unroll
        for (int c = 0; c < 3; ++c) {
            q1r += u0r[c] * u0r[c+1] + u0i[c] * u0i[c+1] + u1r[c] * u1r[c+1] + u1i[c] * u1i[c+1];
            q1i += u0i[c] * u0r[c+1] - u0r[c] * u0i[c+1] + u1i[c] * u1r[c+1] - u1r[c] * u1i[c+1];
        }
#pragma unroll
        for (int c = 0; c < 2; ++c) {
            q2r += u0r[c] * u0r[c+2] + u0i[c] * u0i[c+2] + u1r[c] * u1r[c+2] + u1i[c] * u1i[c+2];
            q2i += u0i[c] * u0r[c+2] - u0r[c] * u0i[c+2] + u1i[c] * u1r[c+2] - u1r[c] * u1i[c+2];
        }
        q3r = u0r[0] * u0r[3] + u0i[0] * u0i[3] + u1r[0] * u1r[3] + u1i[0] * u1i[3];
        q3i = u0i[0] * u0r[3] - u0r[0] * u0i[3] + u1i[0] * u1r[3] - u1r[0] * u1i[3];

        double* o = &tb[f * 7];
        o[0] = T0;
        o[1] = q1r; o[2] = q1i;
        o[3] = q2r; o[4] = q2i;
        o[5] = q3r; o[6] = q3i;
    }
    __syncthreads();

    // ---- phase 3: scan, one thread per angle ----
    if (i < NANGLES) {
        double sum = 0.0;
        double c = c0, s = s0;
#pragma unroll
        for (int k = 0; k < NFREQ; ++k) {
            const double* e = &tb[7 * k];
            const double c2 = c * c - s * s, s2 = 2.0 * c * s;
            const double c3 = c2 * c - s2 * s, s3 = s2 * c + c2 * s;
            const double den = e[0]
                + 2.0 * (e[1] * c - e[2] * s + e[3] * c2 - e[4] * s2 + e[5] * c3 - e[6] * s3)
                + 1e-8;
            sum += 1.0 / den;
            const double cn = c * cd - s * sd;
            s = s * cd + c * sd;
            c = cn;
        }
        out[i] = (float)(sum * (1.0 / 19.0));
    }
}

extern "C" void kernel_launch(void* const* d_in, const int* in_sizes, int n_in,
                              void* d_out, int out_size, void* d_ws, size_t ws_size,
                              hipStream_t stream) {
    const float4* x4 = (const float4*)d_in[0];
    double* ws = (double*)d_ws;          // [0, 608): X coeffs
    float* out = (float*)d_out;

    void* args[] = {(void*)&x4, (void*)&ws, (void*)&out};
    hipLaunchCooperativeKernel(reinterpret_cast<void*>(k_all), dim3(NBLK), dim3(256),
                               args, 0, stream);
}

// Round 4
// 206.916 us; speedup vs baseline: 1.1447x; 1.1447x over previous
//
#include <hip/hip_runtime.h>
#include <math.h>

#define HOP 256
#define T_START 120
#define NFREQ 19
#define KMIN 13
#define NANGLES 18001

// ---------------------------------------------------------------------------
// K12 (fused DFT + eig): one block per frequency k, 4 waves; wave t computes
// the windowed DFT of frame t (identical FP op sequence to the old k_dft:
// each lane handles 8 samples n = lane + 64j for all 4 mics via one float4
// load, trig by recurrence, 2 libm calls/lane, wave shuffle-reduce). Lane 0
// of each wave deposits 8 doubles to LDS. After __syncthreads(), thread 0
// runs the 4x4 complex Jacobi for THIS frequency only (identical op sequence
// to the old k_eig) — 19 Jacobis run in parallel across the 19 blocks, one
// Jacobi of serial latency total, no launch boundary, no global X round-trip.
// ---------------------------------------------------------------------------
__constant__ double C8[8] = {1.0, 0.70710678118654752, 0.0, -0.70710678118654752,
                             -1.0, -0.70710678118654752, 0.0, 0.70710678118654752};
__constant__ double S8[8] = {0.0, 0.70710678118654752, 1.0, 0.70710678118654752,
                             0.0, -0.70710678118654752, -1.0, -0.70710678118654752};

__global__ __launch_bounds__(256) void k_dft_eig(const float4* __restrict__ x4,
                                                 double* __restrict__ tb_g) {
    __shared__ double Xs[4][8];         // [t][2c+ri]
    const int k    = blockIdx.x;
    const int t    = threadIdx.x >> 6;
    const int lane = threadIdx.x & 63;
    const int kact = KMIN + k;
    const int base = (T_START - 1 + t) * HOP;

    // window: (sw,cw) = sin/cos(pi*lane/512); step over 64 samples = pi/8
    const double cw8 = 0.92387953251128675613;  // cos(pi/8)
    const double sw8 = 0.38268343236508977173;  // sin(pi/8)
    double sw, cw;
    sincospi((double)lane / 512.0, &sw, &cw);

    // DFT phase: theta_n = pi*kact*n/256; start at n=lane, step pi*kact/4
    double sp, cp;
    sincospi((double)(kact * lane) / 256.0, &sp, &cp);
    const int m = kact & 7;
    const double cdp = C8[m], sdp = S8[m];

    double xr0 = 0, xi0 = 0, xr1 = 0, xi1 = 0;
    double xr2 = 0, xi2 = 0, xr3 = 0, xi3 = 0;
#pragma unroll
    for (int j = 0; j < 8; ++j) {
        const float4 v = x4[base + lane + 64 * j];
        const double wr = sw * cp;   // w[n]*cos(theta)
        const double wi = sw * sp;   // w[n]*sin(theta)
        xr0 += (double)v.x * wr;  xi0 -= (double)v.x * wi;
        xr1 += (double)v.y * wr;  xi1 -= (double)v.y * wi;
        xr2 += (double)v.z * wr;  xi2 -= (double)v.z * wi;
        xr3 += (double)v.w * wr;  xi3 -= (double)v.w * wi;
        // advance window angle by pi/8
        const double nw = sw * cw8 + cw * sw8;
        cw = cw * cw8 - sw * sw8;
        sw = nw;
        // advance DFT angle by pi*kact/4
        const double np = sp * cdp + cp * sdp;
        cp = cp * cdp - sp * sdp;
        sp = np;
    }
#pragma unroll
    for (int off = 32; off > 0; off >>= 1) {
        xr0 += __shfl_down(xr0, off, 64);  xi0 += __shfl_down(xi0, off, 64);
        xr1 += __shfl_down(xr1, off, 64);  xi1 += __shfl_down(xi1, off, 64);
        xr2 += __shfl_down(xr2, off, 64);  xi2 += __shfl_down(xi2, off, 64);
        xr3 += __shfl_down(xr3, off, 64);  xi3 += __shfl_down(xi3, off, 64);
    }
    if (lane == 0) {
        Xs[t][0] = xr0;  Xs[t][1] = xi0;
        Xs[t][2] = xr1;  Xs[t][3] = xi1;
        Xs[t][4] = xr2;  Xs[t][5] = xi2;
        Xs[t][6] = xr3;  Xs[t][7] = xi3;
    }
    __syncthreads();

    if (threadIdx.x == 0) {
        double Xr[4][4], Xi[4][4];   // [t][c]
#pragma unroll
        for (int tt2 = 0; tt2 < 4; ++tt2)
#pragma unroll
            for (int c = 0; c < 4; ++c) {
                Xr[tt2][c] = Xs[tt2][2 * c];
                Xi[tt2][c] = Xs[tt2][2 * c + 1];
            }

        double Ar[4][4], Ai[4][4], Vr[4][4], Vi[4][4];
#pragma unroll
        for (int aa = 0; aa < 4; ++aa)
#pragma unroll
            for (int dd = 0; dd < 4; ++dd) {
                double ar = 0.0, ai = 0.0;
#pragma unroll
                for (int tt2 = 0; tt2 < 4; ++tt2) {
                    ar += Xr[tt2][aa] * Xr[tt2][dd] + Xi[tt2][aa] * Xi[tt2][dd];
                    ai += Xi[tt2][aa] * Xr[tt2][dd] - Xr[tt2][aa] * Xi[tt2][dd];
                }
                Ar[aa][dd] = 0.25 * ar;
                Ai[aa][dd] = 0.25 * ai;
                Vr[aa][dd] = (aa == dd) ? 1.0 : 0.0;
                Vi[aa][dd] = 0.0;
            }

        // Disjoint-plane pairing: (0,1)(2,3) | (0,2)(1,3) | (0,3)(1,2) —
        // adjacent rotations are data-independent (sqrt/div latencies overlap).
        const int PP[6] = {0, 2, 0, 1, 0, 1};
        const int QQ[6] = {1, 3, 2, 3, 3, 2};
        for (int sweep = 0; sweep < 5; ++sweep) {
#pragma unroll
            for (int r6 = 0; r6 < 6; ++r6) {
                const int p = PP[r6], q = QQ[r6];
                const double zr = Ar[p][q], zi = Ai[p][q];
                const double rr = sqrt(zr * zr + zi * zi);
                if (rr < 1e-30) continue;
                const double tau = (Ar[q][q] - Ar[p][p]) / (2.0 * rr);
                const double sq  = sqrt(tau * tau + 1.0);
                const double tt  = (tau >= 0.0) ? (-1.0 / (tau + sq)) : (1.0 / (sq - tau));
                const double cc  = 1.0 / sqrt(1.0 + tt * tt);
                const double sg  = tt * cc;
                const double inv_r = 1.0 / rr;
                const double sr =  sg * zr * inv_r;
                const double si = -sg * zi * inv_r;
                // A <- A * U
#pragma unroll
                for (int kk = 0; kk < 4; ++kk) {
                    const double apr = Ar[kk][p], api = Ai[kk][p];
                    const double aqr = Ar[kk][q], aqi = Ai[kk][q];
                    Ar[kk][p] = cc * apr + sr * aqr - si * aqi;
                    Ai[kk][p] = cc * api + sr * aqi + si * aqr;
                    Ar[kk][q] = cc * aqr - (sr * apr + si * api);
                    Ai[kk][q] = cc * aqi - (sr * api - si * apr);
                }
                // A <- U^H * A
#pragma unroll
                for (int kk = 0; kk < 4; ++kk) {
                    const double apr = Ar[p][kk], api = Ai[p][kk];
                    const double aqr = Ar[q][kk], aqi = Ai[q][kk];
                    Ar[p][kk] = cc * apr + sr * aqr + si * aqi;
                    Ai[p][kk] = cc * api + sr * aqi - si * aqr;
                    Ar[q][kk] = cc * aqr - (sr * apr - si * api);
                    Ai[q][kk] = cc * aqi - (sr * api + si * apr);
                }
                // V <- V * U
#pragma unroll
                for (int kk = 0; kk < 4; ++kk) {
                    const double vpr = Vr[kk][p], vpi = Vi[kk][p];
                    const double vqr = Vr[kk][q], vqi = Vi[kk][q];
                    Vr[kk][p] = cc * vpr + sr * vqr - si * vqi;
                    Vi[kk][p] = cc * vpi + sr * vqi + si * vqr;
                    Vr[kk][q] = cc * vqr - (sr * vpr + si * vpi);
                    Vi[kk][q] = cc * vqi - (sr * vpi - si * vpr);
                }
            }
        }

        // two smallest eigenvalues -> noise subspace
        double dg[4] = {Ar[0][0], Ar[1][1], Ar[2][2], Ar[3][3]};
        int i0 = 0;
#pragma unroll
        for (int j = 1; j < 4; ++j)
            if (dg[j] < dg[i0]) i0 = j;
        int i1 = (i0 == 0) ? 1 : 0;
#pragma unroll
        for (int j = 0; j < 4; ++j)
            if (j != i0 && dg[j] < dg[i1]) i1 = j;

        double u0r[4], u0i[4], u1r[4], u1i[4];
#pragma unroll
        for (int c = 0; c < 4; ++c) {
            u0r[c] = Vr[c][i0]; u0i[c] = Vi[c][i0];
            u1r[c] = Vr[c][i1]; u1i[c] = Vi[c][i1];
        }

        double T0 = 0.0;
#pragma unroll
        for (int c = 0; c < 4; ++c)
            T0 += u0r[c] * u0r[c] + u0i[c] * u0i[c] + u1r[c] * u1r[c] + u1i[c] * u1i[c];
        double q1r = 0, q1i = 0, q2r = 0, q2i = 0, q3r = 0, q3i = 0;
#pragma unroll
        for (int c = 0; c < 3; ++c) {
            q1r += u0r[c] * u0r[c+1] + u0i[c] * u0i[c+1] + u1r[c] * u1r[c+1] + u1i[c] * u1i[c+1];
            q1i += u0i[c] * u0r[c+1] - u0r[c] * u0i[c+1] + u1i[c] * u1r[c+1] - u1r[c] * u1i[c+1];
        }
#pragma unroll
        for (int c = 0; c < 2; ++c) {
            q2r += u0r[c] * u0r[c+2] + u0i[c] * u0i[c+2] + u1r[c] * u1r[c+2] + u1i[c] * u1i[c+2];
            q2i += u0i[c] * u0r[c+2] - u0r[c] * u0i[c+2] + u1i[c] * u1r[c+2] - u1r[c] * u1i[c+2];
        }
        q3r = u0r[0] * u0r[3] + u0i[0] * u0i[3] + u1r[0] * u1r[3] + u1i[0] * u1i[3];
        q3i = u0i[0] * u0r[3] - u0r[0] * u0i[3] + u1i[0] * u1r[3] - u1r[0] * u1i[3];

        double* o = tb_g + k * 7;
        o[0] = T0;
        o[1] = q1r; o[2] = q1i;
        o[3] = q2r; o[4] = q2i;
        o[5] = q3r; o[6] = q3i;
    }
}

// ---------------------------------------------------------------------------
// K3: one thread per angle (unchanged from the 206.6 µs baseline).
// phi_k = K*sin(theta)*f_k, f_k = 31.25*(13+k); cos/sin advanced by fixed
// rotation over the 19 equally spaced freqs.
// ---------------------------------------------------------------------------
__global__ __launch_bounds__(256) void k_scan(const double* __restrict__ tb_g,
                                              float* __restrict__ out) {
    __shared__ double tb[NFREQ * 7];
    if (threadIdx.x < NFREQ * 7) tb[threadIdx.x] = tb_g[threadIdx.x];
    __syncthreads();
    const int i = blockIdx.x * 256 + threadIdx.x;
    if (i >= NANGLES) return;

    const double deg = -90.0 + 0.01 * (double)i;
    const double sth = sin(deg * (M_PI / 180.0));
    const double KC  = 2.0 * M_PI * 0.1 / 343.0;
    const double a   = KC * sth;

    double c0, s0, cd, sd;
    sincos(a * (31.25 * (double)KMIN), &s0, &c0);
    sincos(a * 31.25, &sd, &cd);

    double sum = 0.0;
#pragma unroll
    for (int k = 0; k < NFREQ; ++k) {
        const double* e = &tb[7 * k];
        const double c2 = c0 * c0 - s0 * s0, s2 = 2.0 * c0 * s0;
        const double c3 = c2 * c0 - s2 * s0, s3 = s2 * c0 + c2 * s0;
        const double den = e[0]
            + 2.0 * (e[1] * c0 - e[2] * s0 + e[3] * c2 - e[4] * s2 + e[5] * c3 - e[6] * s3)
            + 1e-8;
        sum += 1.0 / den;
        const double cn = c0 * cd - s0 * sd;
        s0 = s0 * cd + c0 * sd;
        c0 = cn;
    }
    out[i] = (float)(sum * (1.0 / 19.0));
}

extern "C" void kernel_launch(void* const* d_in, const int* in_sizes, int n_in,
                              void* d_out, int out_size, void* d_ws, size_t ws_size,
                              hipStream_t stream) {
    const float4* x4 = (const float4*)d_in[0];
    double* ws = (double*)d_ws;          // [0, 133): 19 x 7 lag table
    float* out = (float*)d_out;

    hipLaunchKernelGGL(k_dft_eig, dim3(NFREQ), dim3(256), 0, stream, x4, ws);
    hipLaunchKernelGGL(k_scan, dim3((NANGLES + 255) / 256), dim3(256), 0, stream,
                       ws, out);
}